// Round 2
// baseline (756.787 us; speedup 1.0000x reference)
//
#include <hip/hip_runtime.h>
#include <hip/hip_bf16.h>

typedef unsigned short u16;
typedef float floatx4 __attribute__((ext_vector_type(4)));
typedef __bf16 bf16x8 __attribute__((ext_vector_type(8)));

#define NN 8192
#define DD 512

__device__ __forceinline__ u16 f2bf(float f) {
    __hip_bfloat16 h = __float2bfloat16(f);   // RNE
    return __builtin_bit_cast(u16, h);
}
__device__ __forceinline__ float bf2f(u16 u) {
    unsigned v = (unsigned)u << 16;
    return __builtin_bit_cast(float, v);
}

// ---------------------------------------------------------------------------
// Projection GEMM with hi/lo bf16 split (fp32-accurate result):
// out = A(fp32, [8192,512]) @ W(fp32, [512,512])
// z=0: Q = x1@q -> Qh,Ql (row-major hi/lo bf16)
// z=1: K = x2@k -> Kh,Kl
// z=2: VT = (x1@v)^T -> bf16 (hi only; storage error is below the noise floor)
// 128x128 tile, BK=32, 4 waves 2x2, wave tile 64x64 (4x4 MFMA 16x16x32, 3 terms)
// ---------------------------------------------------------------------------
__global__ __launch_bounds__(256, 2)
void proj_kernel(const float* __restrict__ x1, const float* __restrict__ x2,
                 const float* __restrict__ qw, const float* __restrict__ kw,
                 const float* __restrict__ vw,
                 u16* __restrict__ Qh, u16* __restrict__ Ql,
                 u16* __restrict__ Kh, u16* __restrict__ Kl,
                 u16* __restrict__ VT)
{
    const int which = blockIdx.z;
    const float* A = (which == 1) ? x2 : x1;
    const float* W = (which == 0) ? qw : (which == 1 ? kw : vw);

    __shared__ u16 Ash[128 * 40], Asl[128 * 40];  // [m][k]
    __shared__ u16 Wsh[128 * 40], Wsl[128 * 40];  // [n][k] (W transposed)

    const int tid  = threadIdx.x;
    const int lane = tid & 63;
    const int wave = tid >> 6;
    const int l15  = lane & 15;
    const int quad = lane >> 4;
    const int wm   = (wave & 1) * 64;
    const int wn   = (wave >> 1) * 64;
    const int m0   = blockIdx.x * 128;
    const int n0   = blockIdx.y * 128;

    floatx4 acc[4][4] = {};

    for (int k0 = 0; k0 < DD; k0 += 32) {
        __syncthreads();
        // Stage A tile: 128 rows x 32 cols fp32 -> hi/lo bf16 LDS [m][k]
        {
            const int cg = (tid & 7) * 4;
            for (int i = 0; i < 4; i++) {
                const int row = (tid >> 3) + i * 32;
                float4 f = *(const float4*)&A[(size_t)(m0 + row) * DD + k0 + cg];
                u16 hx = f2bf(f.x), hy = f2bf(f.y), hz = f2bf(f.z), hw = f2bf(f.w);
                uint2 ph, pl;
                ph.x = ((unsigned)hy << 16) | hx;
                ph.y = ((unsigned)hw << 16) | hz;
                pl.x = ((unsigned)f2bf(f.y - bf2f(hy)) << 16) | f2bf(f.x - bf2f(hx));
                pl.y = ((unsigned)f2bf(f.w - bf2f(hw)) << 16) | f2bf(f.z - bf2f(hz));
                *(uint2*)&Ash[row * 40 + cg] = ph;
                *(uint2*)&Asl[row * 40 + cg] = pl;
            }
        }
        // Stage W tile: 32 rows(k) x 128 cols(n) -> hi/lo LDS [n][k]
        {
            const int kr = tid & 31;
            const int g  = tid >> 5;
            for (int i = 0; i < 4; i++) {
                const int n = (g + i * 8) * 4;
                float4 f = *(const float4*)&W[(size_t)(k0 + kr) * DD + n0 + n];
                float e[4] = {f.x, f.y, f.z, f.w};
                for (int j = 0; j < 4; j++) {
                    u16 h = f2bf(e[j]);
                    Wsh[(n + j) * 40 + kr] = h;
                    Wsl[(n + j) * 40 + kr] = f2bf(e[j] - bf2f(h));
                }
            }
        }
        __syncthreads();

        bf16x8 ah[4], al[4], bh[4], bl[4];
        for (int mi = 0; mi < 4; mi++) {
            ah[mi] = *(const bf16x8*)&Ash[(wm + mi * 16 + l15) * 40 + quad * 8];
            al[mi] = *(const bf16x8*)&Asl[(wm + mi * 16 + l15) * 40 + quad * 8];
        }
        for (int ni = 0; ni < 4; ni++) {
            bh[ni] = *(const bf16x8*)&Wsh[(wn + ni * 16 + l15) * 40 + quad * 8];
            bl[ni] = *(const bf16x8*)&Wsl[(wn + ni * 16 + l15) * 40 + quad * 8];
        }
        for (int mi = 0; mi < 4; mi++)
            for (int ni = 0; ni < 4; ni++) {
                acc[mi][ni] = __builtin_amdgcn_mfma_f32_16x16x32_bf16(ah[mi], bh[ni], acc[mi][ni], 0, 0, 0);
                acc[mi][ni] = __builtin_amdgcn_mfma_f32_16x16x32_bf16(ah[mi], bl[ni], acc[mi][ni], 0, 0, 0);
                acc[mi][ni] = __builtin_amdgcn_mfma_f32_16x16x32_bf16(al[mi], bh[ni], acc[mi][ni], 0, 0, 0);
            }
    }

    // Epilogue: C/D layout col = lane&15, row = quad*4 + reg
    for (int mi = 0; mi < 4; mi++)
        for (int ni = 0; ni < 4; ni++)
            for (int r = 0; r < 4; r++) {
                const int row = m0 + wm + mi * 16 + quad * 4 + r;
                const int col = n0 + wn + ni * 16 + l15;
                const float v = acc[mi][ni][r];
                const u16 hv = f2bf(v);
                if (which == 0) {
                    Qh[(size_t)row * DD + col] = hv;
                    Ql[(size_t)row * DD + col] = f2bf(v - bf2f(hv));
                } else if (which == 1) {
                    Kh[(size_t)row * DD + col] = hv;
                    Kl[(size_t)row * DD + col] = f2bf(v - bf2f(hv));
                } else {
                    VT[(size_t)col * NN + row] = hv;
                }
            }
}

// ---------------------------------------------------------------------------
// Flash attention partials. Grid (128 row-blocks, 4 j-parts), 256 thr.
// Block: 64 Q rows (16/wave). BN=64 K rows/iter; D=512 in per-wave acc.
// QK^T uses 3-term hi/lo split -> fp32-accurate logits.
// Writes un-normalized O + (m,l) per part.
// ---------------------------------------------------------------------------
__global__ __launch_bounds__(256, 2)
void attn_kernel(const u16* __restrict__ Qh, const u16* __restrict__ Ql,
                 const u16* __restrict__ Kh, const u16* __restrict__ Kl,
                 const u16* __restrict__ VT,
                 float* __restrict__ Opart, float* __restrict__ Mp,
                 float* __restrict__ Lp)
{
    const int rb   = blockIdx.x;
    const int part = blockIdx.y;
    const int tid  = threadIdx.x;
    const int lane = tid & 63;
    const int wave = tid >> 6;
    const int l15  = lane & 15;
    const int quad = lane >> 4;

    __shared__ u16 Ksh[64 * 136];      // K hi chunk [j][d]: 64 x 128
    __shared__ u16 Ksl[64 * 136];      // K lo chunk
    __shared__ u16 Vs[128 * 72];       // V^T chunk [d][j]: 128 x 64
    __shared__ u16 Ps[4][16 * 72];     // per-wave P [qrow][j]: 16 x 64

    const int q0 = rb * 64 + wave * 16;   // wave's Q rows

    floatx4 o[32] = {};                   // O: 16 rows x 512 cols (C-layout)
    float m_run[4], l_run[4];
    for (int r = 0; r < 4; r++) { m_run[r] = -1e30f; l_run[r] = 0.f; }

    const int j_begin = part * 2048;
    const int j_end   = j_begin + 2048;

    for (int j0 = j_begin; j0 < j_end; j0 += 64) {
        // ---- S = Q K^T over this 64-row K tile (full D=512, 3-term split) ----
        floatx4 s[4] = {};
        for (int dc = 0; dc < 4; dc++) {
            __syncthreads();
            {   // stage K rows j0..j0+64, cols dc*128..+128 (hi and lo)
                const int dd = (tid & 15) * 8;
                for (int i = 0; i < 4; i++) {
                    const int jj = (tid >> 4) + i * 16;
                    *(uint4*)&Ksh[jj * 136 + dd] =
                        *(const uint4*)&Kh[(size_t)(j0 + jj) * DD + dc * 128 + dd];
                    *(uint4*)&Ksl[jj * 136 + dd] =
                        *(const uint4*)&Kl[(size_t)(j0 + jj) * DD + dc * 128 + dd];
                }
            }
            __syncthreads();
            bf16x8 qhf[4], qlf[4];
            for (int ks = 0; ks < 4; ks++) {
                qhf[ks] = *(const bf16x8*)&Qh[(size_t)(q0 + l15) * DD + dc * 128 + ks * 32 + quad * 8];
                qlf[ks] = *(const bf16x8*)&Ql[(size_t)(q0 + l15) * DD + dc * 128 + ks * 32 + quad * 8];
            }
            for (int ks = 0; ks < 4; ks++)
                for (int nt = 0; nt < 4; nt++) {
                    bf16x8 kh = *(const bf16x8*)&Ksh[(nt * 16 + l15) * 136 + ks * 32 + quad * 8];
                    bf16x8 kl = *(const bf16x8*)&Ksl[(nt * 16 + l15) * 136 + ks * 32 + quad * 8];
                    s[nt] = __builtin_amdgcn_mfma_f32_16x16x32_bf16(qhf[ks], kh, s[nt], 0, 0, 0);
                    s[nt] = __builtin_amdgcn_mfma_f32_16x16x32_bf16(qhf[ks], kl, s[nt], 0, 0, 0);
                    s[nt] = __builtin_amdgcn_mfma_f32_16x16x32_bf16(qlf[ks], kh, s[nt], 0, 0, 0);
                }
        }

        // ---- leaky_relu + online softmax ----
        for (int nt = 0; nt < 4; nt++)
            for (int r = 0; r < 4; r++) {
                float x = s[nt][r];
                s[nt][r] = x >= 0.f ? x : 0.01f * x;
            }
        float mt[4];
        for (int r = 0; r < 4; r++)
            mt[r] = fmaxf(fmaxf(s[0][r], s[1][r]), fmaxf(s[2][r], s[3][r]));
        for (int off = 1; off < 16; off <<= 1)
            for (int r = 0; r < 4; r++)
                mt[r] = fmaxf(mt[r], __shfl_xor(mt[r], off));

        float alpha[4];
        for (int r = 0; r < 4; r++) {
            const float mnew = fmaxf(m_run[r], mt[r]);
            alpha[r] = __expf(m_run[r] - mnew);
            m_run[r] = mnew;
        }
        float ls[4] = {0.f, 0.f, 0.f, 0.f};
        u16 pv[4][4];
        for (int nt = 0; nt < 4; nt++)
            for (int r = 0; r < 4; r++) {
                const float p = __expf(s[nt][r] - m_run[r]);
                ls[r] += p;
                pv[nt][r] = f2bf(p);
            }
        for (int off = 1; off < 16; off <<= 1)
            for (int r = 0; r < 4; r++)
                ls[r] += __shfl_xor(ls[r], off);
        for (int r = 0; r < 4; r++)
            l_run[r] = l_run[r] * alpha[r] + ls[r];
        for (int i = 0; i < 32; i++)
            for (int r = 0; r < 4; r++)
                o[i][r] *= alpha[r];

        // ---- P: C-layout -> A-layout via per-wave LDS (same-wave, waitcnt only) ----
        for (int nt = 0; nt < 4; nt++)
            for (int r = 0; r < 4; r++)
                Ps[wave][(quad * 4 + r) * 72 + nt * 16 + l15] = pv[nt][r];
        asm volatile("s_waitcnt lgkmcnt(0)" ::: "memory");
        bf16x8 pf[2];
        for (int ks = 0; ks < 2; ks++)
            pf[ks] = *(const bf16x8*)&Ps[wave][l15 * 72 + ks * 32 + quad * 8];

        // ---- O += P @ V ----
        for (int dc = 0; dc < 4; dc++) {
            __syncthreads();
            {   // stage V^T rows dc*128..+128, cols j0..j0+64
                const int cg = (tid & 7) * 8;
                for (int i = 0; i < 4; i++) {
                    const int dr = (tid >> 3) + i * 32;
                    *(uint4*)&Vs[dr * 72 + cg] =
                        *(const uint4*)&VT[(size_t)(dc * 128 + dr) * NN + j0 + cg];
                }
            }
            __syncthreads();
            for (int nt2 = 0; nt2 < 8; nt2++) {
                bf16x8 b0 = *(const bf16x8*)&Vs[(nt2 * 16 + l15) * 72 + quad * 8];
                bf16x8 b1 = *(const bf16x8*)&Vs[(nt2 * 16 + l15) * 72 + 32 + quad * 8];
                o[dc * 8 + nt2] = __builtin_amdgcn_mfma_f32_16x16x32_bf16(pf[0], b0, o[dc * 8 + nt2], 0, 0, 0);
                o[dc * 8 + nt2] = __builtin_amdgcn_mfma_f32_16x16x32_bf16(pf[1], b1, o[dc * 8 + nt2], 0, 0, 0);
            }
        }
    }

    // ---- write partials ----
    for (int i = 0; i < 32; i++)
        for (int r = 0; r < 4; r++) {
            const int row = q0 + quad * 4 + r;
            const int col = i * 16 + l15;
            Opart[((size_t)part * NN + row) * DD + col] = o[i][r];
        }
    if (l15 == 0)
        for (int r = 0; r < 4; r++) {
            const int row = q0 + quad * 4 + r;
            Mp[part * NN + row] = m_run[r];
            Lp[part * NN + row] = l_run[r];
        }
}

// ---------------------------------------------------------------------------
// Combine 4 j-partials: out = sum_p exp(m_p - M) O_p / sum_p exp(m_p - M) l_p
// ---------------------------------------------------------------------------
__global__ __launch_bounds__(256)
void combine_kernel(const float* __restrict__ Opart, const float* __restrict__ Mp,
                    const float* __restrict__ Lp, float* __restrict__ out)
{
    const int row = blockIdx.x;
    const int tid = threadIdx.x;
    float m[4], l[4];
    for (int p = 0; p < 4; p++) { m[p] = Mp[p * NN + row]; l[p] = Lp[p * NN + row]; }
    float M = fmaxf(fmaxf(m[0], m[1]), fmaxf(m[2], m[3]));
    float w[4], L = 0.f;
    for (int p = 0; p < 4; p++) { w[p] = __expf(m[p] - M); L += w[p] * l[p]; }
    const float inv = 1.f / L;
    for (int d = tid; d < DD; d += 256) {
        float acc = 0.f;
        for (int p = 0; p < 4; p++)
            acc += w[p] * Opart[((size_t)p * NN + row) * DD + d];
        out[(size_t)row * DD + d] = acc * inv;
    }
}

// ---------------------------------------------------------------------------
extern "C" void kernel_launch(void* const* d_in, const int* in_sizes, int n_in,
                              void* d_out, int out_size, void* d_ws, size_t ws_size,
                              hipStream_t stream)
{
    const float* x1 = (const float*)d_in[0];
    const float* x2 = (const float*)d_in[1];
    const float* qw = (const float*)d_in[2];
    const float* kw = (const float*)d_in[3];
    const float* vw = (const float*)d_in[4];
    float* out = (float*)d_out;

    // workspace layout: Qh|Ql|Kh|Kl|VT (8MB each, bf16) | Opart 64MB fp32 | Mp | Lp
    u16* Qh = (u16*)d_ws;
    u16* Ql = Qh + (size_t)NN * DD;
    u16* Kh = Ql + (size_t)NN * DD;
    u16* Kl = Kh + (size_t)NN * DD;
    u16* VT = Kl + (size_t)NN * DD;
    float* Opart = (float*)(VT + (size_t)NN * DD);
    float* Mp = Opart + (size_t)4 * NN * DD;
    float* Lp = Mp + 4 * NN;

    proj_kernel<<<dim3(64, 4, 3), 256, 0, stream>>>(x1, x2, qw, kw, vw, Qh, Ql, Kh, Kl, VT);
    attn_kernel<<<dim3(128, 4), 256, 0, stream>>>(Qh, Ql, Kh, Kl, VT, Opart, Mp, Lp);
    combine_kernel<<<NN, 256, 0, stream>>>(Opart, Mp, Lp, out);
}